// Round 1
// baseline (279.630 us; speedup 1.0000x reference)
//
#include <hip/hip_runtime.h>
#include <math.h>

#define NUM_BINS 100
#define EPS 1e-6f

// ws layout (uint32): [0..99] pos-bin counts, [100..199] neg-bin counts, [200] pos pixel count
#define WS_WORDS (2 * NUM_BINS + 1)

__global__ void hml_init_ws(unsigned int* __restrict__ ws) {
    int i = blockIdx.x * blockDim.x + threadIdx.x;
    if (i < WS_WORDS) ws[i] = 0u;
}

__global__ __launch_bounds__(256) void hml_hist(
    const float* __restrict__ f0, const float* __restrict__ f1,
    const int* __restrict__ gt, unsigned int* __restrict__ ws,
    int hw, int C)
{
    __shared__ unsigned int sh[WS_WORDS];
    for (int i = threadIdx.x; i < WS_WORDS; i += blockDim.x) sh[i] = 0u;
    __syncthreads();

    const int hw4 = hw >> 2;                       // pixels processed 4 at a time
    const int idx = blockIdx.x * blockDim.x + threadIdx.x;

    if (idx < hw4) {
        const float4* __restrict__ f0v = (const float4*)f0;
        const float4* __restrict__ f1v = (const float4*)f1;
        float s0 = 0.f, s1 = 0.f, s2 = 0.f, s3 = 0.f;
        #pragma unroll 4
        for (int c = 0; c < C; ++c) {
            float4 a = f0v[(size_t)c * hw4 + idx];
            float4 b = f1v[(size_t)c * hw4 + idx];
            float d0 = a.x - b.x + EPS;
            float d1 = a.y - b.y + EPS;
            float d2 = a.z - b.z + EPS;
            float d3 = a.w - b.w + EPS;
            s0 = fmaf(d0, d0, s0);
            s1 = fmaf(d1, d1, s1);
            s2 = fmaf(d2, d2, s2);
            s3 = fmaf(d3, d3, s3);
        }
        int4 g = ((const int4*)gt)[idx];

        float d[4] = { sqrtf(s0), sqrtf(s1), sqrtf(s2), sqrtf(s3) };
        int   gg[4] = { g.x, g.y, g.z, g.w };

        int posc = 0;
        #pragma unroll
        for (int k = 0; k < 4; ++k) {
            posc += (gg[k] == 0) ? 1 : 0;
            float dd = d[k];
            // histc semantics: values in [0,1] only; floor(d*100) clipped to [0,99]
            if (dd <= 1.0f) {                       // dd >= 0 always (sqrt)
                int bin = (int)(dd * (float)NUM_BINS);
                if (bin > NUM_BINS - 1) bin = NUM_BINS - 1;
                atomicAdd(&sh[bin + ((gg[k] != 0) ? NUM_BINS : 0)], 1u);
            }
        }
        if (posc) atomicAdd(&sh[2 * NUM_BINS], (unsigned)posc);
    }
    __syncthreads();

    for (int i = threadIdx.x; i < WS_WORDS; i += blockDim.x) {
        unsigned v = sh[i];
        if (v) atomicAdd(&ws[i], v);
    }
}

__global__ void hml_final(const unsigned int* __restrict__ ws,
                          float* __restrict__ out, int hw)
{
    __shared__ float terms[NUM_BINS];
    int i = threadIdx.x;
    unsigned pos = ws[2 * NUM_BINS];
    float pos_size = (float)pos;
    float neg_size = (float)(hw - (int)pos);
    if (i < NUM_BINS) {
        float hp = (float)ws[i] / pos_size;
        unsigned cn = ws[NUM_BINS + i];
        float hn = (float)cn / neg_size;
        terms[i] = (cn > 0u) ? hn * (logf(hn) - hp) : 0.0f;
    }
    __syncthreads();
    if (i == 0) {
        float s = 0.f;
        for (int k = 0; k < NUM_BINS; ++k) s += terms[k];
        out[0] = 1.0f + s / (float)NUM_BINS;
    }
}

extern "C" void kernel_launch(void* const* d_in, const int* in_sizes, int n_in,
                              void* d_out, int out_size, void* d_ws, size_t ws_size,
                              hipStream_t stream) {
    const float* f0 = (const float*)d_in[0];
    const float* f1 = (const float*)d_in[1];
    const int*   gt = (const int*)d_in[2];
    float* out = (float*)d_out;
    unsigned int* ws = (unsigned int*)d_ws;

    const int hw = in_sizes[2];          // h*w (= 1024*1024)
    const int C  = in_sizes[0] / hw;     // channels (= 32)

    hml_init_ws<<<1, 256, 0, stream>>>(ws);

    const int hw4 = hw >> 2;
    const int threads = 256;
    const int blocks = (hw4 + threads - 1) / threads;
    hml_hist<<<blocks, threads, 0, stream>>>(f0, f1, gt, ws, hw, C);

    hml_final<<<1, 128, 0, stream>>>(ws, out, hw);
}